// Round 20
// baseline (202.157 us; speedup 1.0000x reference)
//
#include <hip/hip_runtime.h>
#include <math.h>

#define NBLK  11
#define NAGG  4
#define NFILT 32
#define NPROP 20
#define BB    128
#define VV    1024
#define PARTS 4
#define PV    256     // vertices per group (quarter event)
#define FIN   10
#define TPB   512
#define BN_EPS 1e-3f
#define SHS   40      // sH row stride in halves (80 B)
#define SFTS  264     // sFT col stride in halves (528 B)

// d_ws floats — r9-proven layout: flags[128]; mean[b][part][10]; agg[(b*2+par)*4+part][192];
// then OPTIONAL frag table (guarded by ws_size).
#define WSF_MEAN 128
#define WSF_AGG  (WSF_MEAN + BB*PARTS*FIN)              // 5248
#define WSF_END  (WSF_AGG + (BB*2) * PARTS * NAGG * 48) // 201856 floats = 807 KB (r9-proven fits)
#define NFRAG    (NBLK*7*64*8)                          // 39424 f16 = 79 KB

typedef _Float16 f16;
typedef f16   f16x4 __attribute__((ext_vector_type(4)));
typedef f16   f16x8 __attribute__((ext_vector_type(8)));
typedef float f32x4 __attribute__((ext_vector_type(4)));

__device__ __forceinline__ f32x4 MFMA(f16x8 a, f16x8 b, f32x4 c){
  return __builtin_amdgcn_mfma_f32_16x16x32_f16(a, b, c, 0, 0, 0);
}

__device__ __forceinline__ float fast_tanh(float x){
  float a = fabsf(x);
  float e = __expf(-2.0f * a);
  float r = (1.0f - e) / (1.0f + e);
  return copysignf(r, x);
}

// prep: f16 B-fragment table (r15-proven).
extern "C" __global__ void garnet_prep(
    const float* __restrict__ W_flr, const float* __restrict__ W_s,
    const float* __restrict__ W_out, const float* __restrict__ W_o0,
    f16* __restrict__ frag)
{
  const int idx = blockIdx.x * blockDim.x + threadIdx.x;
  if (idx >= NFRAG) return;
  const int j    = idx & 7;
  const int lane = (idx >> 3) & 63;
  const int rest = idx >> 9;
  const int set  = rest % 7;
  const int l    = rest / 7;
  const int l16  = lane & 15, kb = lane >> 4, k = kb*8 + j;
  float val = 0.f;
  if (set < 2){
    const int n = set*16 + l16;
    if (set == 0) val = W_flr[l*NFILT*NPROP + k*NPROP + n];
    else          val = (n < 20) ? W_flr[l*NFILT*NPROP + k*NPROP + n]
                       : (n < 24 ? W_s[l*NFILT*NAGG + k*NAGG + (n-20)] : 0.f);
  } else if (set < 4){
    const int s = set - 2;
    val = W_out[l*228*NFILT + k*NFILT + s*16 + l16];
  } else {
    const int s = set - 4;
    val = W_o0[((size_t)l*NFILT + k)*48 + s*16 + l16];
  }
  frag[idx] = (f16)val;
}

// 256 WGs (1/CU guaranteed resident). Each WG = TWO independent 4-wave groups,
// each owning a quarter of a DIFFERENT event (gid = wg*2+grp; b=gid&127,
// part=gid>>7; all 4 parts of an event at wg offsets 0/64/128/192 -> same XCD).
// Groups sync internally via LDS-counter barriers (never __syncthreads, which
// would couple them); cross-WG 4-way flag sync per event (r9 layout). While
// one group's poster spins, the other group's 4 waves keep the SIMDs fed.
// MFMA 16x16x32 frags (m89-verified): A[row=lane&15][k=8*(lane>>4)+j],
// B[k][col=lane&15], C[row=4*(lane>>4)+q][col=lane&15].
extern "C" __global__ __launch_bounds__(TPB)
void garnet_fused(
    const float* __restrict__ x,
    const float* __restrict__ bn0_g, const float* __restrict__ bn0_b,
    const float* __restrict__ bn0_m, const float* __restrict__ bn0_v,
    const float* __restrict__ W_in,  const float* __restrict__ b_in,
    const float* __restrict__ W_flr, const float* __restrict__ b_flr,
    const float* __restrict__ W_s,   const float* __restrict__ b_s,
    const float* __restrict__ W_out, const float* __restrict__ b_out,
    const float* __restrict__ bn_g,  const float* __restrict__ bn_b,
    const float* __restrict__ bn_m,  const float* __restrict__ bn_v,
    const float* __restrict__ W_o0,  const float* __restrict__ b_o0,
    const float* __restrict__ W_o1,  const float* __restrict__ b_o1,
    int* __restrict__ wsFlag, float* __restrict__ wsF,
    const f16* __restrict__ frag,
    float* __restrict__ out)
{
  const int wg   = blockIdx.x;
  const int t    = threadIdx.x;
  const int lane = t & 63;
  const int wave = t >> 6;
  const int grp  = wave >> 2;          // 0/1: which independent group
  const int wv   = wave & 3;           // wave within group
  const int tl   = t & 255;            // thread within group (row owned)
  const int gid  = wg * 2 + grp;       // global group id 0..511
  const int b    = gid & (BB - 1);     // event
  const int part = gid >> 7;           // 0..3
  const int l16  = lane & 15;
  const int kb   = lane >> 4;

  __shared__ __align__(16) f16 sHhi[2][PV * SHS];   // 2 x 20 KB
  __shared__ __align__(16) f16 sHlo[2][PV * SHS];   // 2 x 20 KB
  __shared__ __align__(16) f16 sFT[2][20 * SFTS];   // 2 x 10.3 KB
  __shared__ __align__(16) float sW[2][PV * 4];     // 2 x 4 KB
  __shared__ f16   sMh[2][4 * 32];
  __shared__ float sAgg[2][NAGG][48];
  __shared__ float sRed[2][4][FIN];
  __shared__ float sMean[2][FIN];
  __shared__ int   gcnt[2];

  int* flag = wsFlag + b;
  int gbt = 0;   // group-barrier target (increments by 4 per barrier)

  // group barrier: drain this wave's LDS+VMEM, bump counter, spin (LDS broadcast).
  auto grpbar = [&](){
    gbt += 4;
    asm volatile("s_waitcnt vmcnt(0) lgkmcnt(0)" ::: "memory");
    if (lane == 0)
      __hip_atomic_fetch_add(&gcnt[grp], 1, __ATOMIC_RELAXED, __HIP_MEMORY_SCOPE_WORKGROUP);
    while (__hip_atomic_load(&gcnt[grp], __ATOMIC_RELAXED, __HIP_MEMORY_SCOPE_WORKGROUP) < gbt)
      __builtin_amdgcn_s_sleep(1);
    asm volatile("" ::: "memory");
  };

  if (t < 2) gcnt[t] = 0;
  __syncthreads();     // ONLY full-WG sync (barrier-counter init); groups decouple after.

  f32x4 acc[4][3];

  // phaseC(lc): acc += out_lc @ W_o0_slice(lc); reads own-wave sH rows only.
  auto phaseC = [&](int lc){
    f16x8 b3f[3];
    if (frag){
      const f16* flC = frag + (size_t)lc * 7 * 64 * 8;
      #pragma unroll
      for (int s = 0; s < 3; ++s)
        b3f[s] = *(const f16x8*)&flC[(size_t)((4 + s)*64 + lane)*8];
    } else {
      const float* Wo0l = W_o0 + (size_t)lc * NFILT * 48;
      #pragma unroll
      for (int s = 0; s < 3; ++s)
        #pragma unroll
        for (int j = 0; j < 8; ++j)
          b3f[s][j] = (f16)Wo0l[(kb*8 + j)*48 + s*16 + l16];
    }
    #pragma unroll
    for (int i = 0; i < 4; ++i){
      const int tb = wv*64 + i*16;
      const f16x8 ahi = *(const f16x8*)&sHhi[grp][(tb + l16)*SHS + kb*8];
      const f16x8 alo = *(const f16x8*)&sHlo[grp][(tb + l16)*SHS + kb*8];
      #pragma unroll
      for (int s = 0; s < 3; ++s){
        acc[i][s] = MFMA(ahi, b3f[s], acc[i][s]);
        acc[i][s] = MFMA(alo, b3f[s], acc[i][s]);
      }
    }
  };

  // ---------------- phase 0: mean over V (4-way) + input dense ----------------
  {
    float xv[FIN];
    const float* xp = x + ((size_t)b * VV + part * PV + tl) * FIN;
    #pragma unroll
    for (int c = 0; c < FIN; ++c) xv[c] = xp[c];

    float ps[FIN];
    #pragma unroll
    for (int c = 0; c < FIN; ++c) ps[c] = xv[c];
    #pragma unroll
    for (int m = 32; m > 0; m >>= 1){
      #pragma unroll
      for (int c = 0; c < FIN; ++c) ps[c] += __shfl_xor(ps[c], m, 64);
    }
    if (lane == 0){
      #pragma unroll
      for (int c = 0; c < FIN; ++c) sRed[grp][wv][c] = ps[c];
    }
    grpbar();
    if (tl < FIN){
      float s = 0.f;
      #pragma unroll
      for (int w_ = 0; w_ < 4; ++w_) s += sRed[grp][w_][tl];
      __hip_atomic_store(&wsF[WSF_MEAN + (b*PARTS + part)*FIN + tl], s,
                         __ATOMIC_RELAXED, __HIP_MEMORY_SCOPE_AGENT);
    }
    grpbar();                         // drains the ws stores (vmcnt in barrier)
    if (tl == 0){
      __hip_atomic_fetch_add(flag, 1, __ATOMIC_RELAXED, __HIP_MEMORY_SCOPE_AGENT);
      while (__hip_atomic_load(flag, __ATOMIC_RELAXED, __HIP_MEMORY_SCOPE_AGENT) < PARTS)
        __builtin_amdgcn_s_sleep(2);
    }
    grpbar();
    if (tl < FIN){
      float s = 0.f;
      #pragma unroll
      for (int p = 0; p < PARTS; ++p)
        s += __hip_atomic_load(&wsF[WSF_MEAN + (b*PARTS + p)*FIN + tl],
                               __ATOMIC_RELAXED, __HIP_MEMORY_SCOPE_AGENT);
      sMean[grp][tl] = s * (1.0f / VV);
    }
    grpbar();

    float o[NFILT];
    #pragma unroll
    for (int j = 0; j < NFILT; ++j) o[j] = b_in[j];
    #pragma unroll
    for (int c = 0; c < FIN; ++c){
      const float zx = (xv[c]         - bn0_m[c])     * (bn0_g[c]     * rsqrtf(bn0_v[c]     + BN_EPS)) + bn0_b[c];
      const float zm = (sMean[grp][c] - bn0_m[FIN+c]) * (bn0_g[FIN+c] * rsqrtf(bn0_v[FIN+c] + BN_EPS)) + bn0_b[FIN+c];
      #pragma unroll
      for (int j = 0; j < NFILT; ++j)
        o[j] += zx * W_in[c*NFILT + j] + zm * W_in[(FIN+c)*NFILT + j];
    }
    #pragma unroll
    for (int cc = 0; cc < 4; ++cc){
      f16x8 hh, hl;
      #pragma unroll
      for (int j = 0; j < 8; ++j){
        const float hv = fast_tanh(o[cc*8 + j]);
        const f16 a = (f16)hv;
        hh[j] = a;
        hl[j] = (f16)(hv - (float)a);
      }
      *(f16x8*)&sHhi[grp][tl*SHS + cc*8] = hh;
      *(f16x8*)&sHlo[grp][tl*SHS + cc*8] = hl;
    }
    grpbar();                         // stage1 reads other threads' rows
  }

  #pragma unroll
  for (int s = 0; s < 3; ++s){
    const float a0 = b_o0[s*16 + l16];
    #pragma unroll
    for (int i = 0; i < 4; ++i) acc[i][s] = (f32x4){a0, a0, a0, a0};
  }

  for (int l = 0; l < NBLK; ++l){
    const float* Wf = W_flr + l * NFILT * NPROP;
    const float* bf = b_flr + l * NPROP;
    const float* Ws = W_s   + l * NFILT * NAGG;
    const float* bs = b_s   + l * NAGG;
    const float* Wo = W_out + l * 228 * NFILT;
    const float* bo = b_out + l * NFILT;
    const float* g_ = bn_g  + l * NFILT;
    const float* be = bn_b  + l * NFILT;
    const float* bm = bn_m  + l * NFILT;
    const float* bv = bn_v  + l * NFILT;
    const f16*  fl  = frag + (size_t)l * 7 * 64 * 8;

    // ---- stage 1 (MFMA): feat = h @ [Wf|Ws]; f -> sFT f16, w -> sW f32 ----
    {
      f16x8 b1f0, b1f1;
      if (frag){
        b1f0 = *(const f16x8*)&fl[(size_t)(0*64 + lane)*8];
        b1f1 = *(const f16x8*)&fl[(size_t)(1*64 + lane)*8];
      } else {
        #pragma unroll
        for (int j = 0; j < 8; ++j){
          const int k = kb*8 + j;
          b1f0[j] = (f16)Wf[k*NPROP + l16];
          const int n = 16 + l16;
          b1f1[j] = (f16)((n < 20) ? Wf[k*NPROP + n] : (n < 24 ? Ws[k*NAGG + (n-20)] : 0.f));
        }
      }
      const float bias0 = bf[l16];
      const int  c1 = 16 + l16;
      const float bias1 = (c1 < 20) ? bf[c1] : (c1 < 24 ? bs[c1-20] : 0.f);

      #pragma unroll
      for (int i = 0; i < 4; ++i){
        const int tb = wv*64 + i*16;
        const f16x8 ahi = *(const f16x8*)&sHhi[grp][(tb + l16)*SHS + kb*8];
        const f16x8 alo = *(const f16x8*)&sHlo[grp][(tb + l16)*SHS + kb*8];
        f32x4 c0 = (f32x4){bias0, bias0, bias0, bias0};
        c0 = MFMA(ahi, b1f0, c0);
        c0 = MFMA(alo, b1f0, c0);
        f16x4 s0;
        #pragma unroll
        for (int q = 0; q < 4; ++q) s0[q] = (f16)c0[q];
        *(f16x4*)&sFT[grp][l16*SFTS + tb + kb*4] = s0;

        f32x4 c1v = (f32x4){bias1, bias1, bias1, bias1};
        c1v = MFMA(ahi, b1f1, c1v);
        c1v = MFMA(alo, b1f1, c1v);
        if (l16 < 4){
          f16x4 s1;
          #pragma unroll
          for (int q = 0; q < 4; ++q) s1[q] = (f16)c1v[q];
          *(f16x4*)&sFT[grp][(16 + l16)*SFTS + tb + kb*4] = s1;
        } else if (l16 < 8){
          #pragma unroll
          for (int q = 0; q < 4; ++q)
            sW[grp][(tb + kb*4 + q)*4 + (l16 - 4)] = __expf(-fabsf(c1v[q]));
        }
      }
    }
    grpbar();

    // ---- stage 2: max/sum over 256 rows; wave owns 6 cols as 2 passes of 3 ----
    // cols 0..19 = f (sFT), 20..23 = w (sW) -- w aggregates over itself.
    #pragma unroll
    for (int pass = 0; pass < 2; ++pass){
      const int w3 = wv * 6 + pass * 3;
      float psum[NAGG][3], pmax[NAGG][3];
      #pragma unroll
      for (int a = 0; a < NAGG; ++a)
        #pragma unroll
        for (int c = 0; c < 3; ++c){ psum[a][c] = 0.f; pmax[a][c] = -INFINITY; }
      #pragma unroll
      for (int i = 0; i < 4; ++i){
        const int row = i * 64 + lane;
        const f32x4 wvv = *(const f32x4*)&sW[grp][row*4];
        float fc[3];
        #pragma unroll
        for (int c = 0; c < 3; ++c){
          const int col = w3 + c;
          fc[c] = (col < 20) ? (float)sFT[grp][col*SFTS + row] : wvv[col - 20];
        }
        #pragma unroll
        for (int a = 0; a < NAGG; ++a)
          #pragma unroll
          for (int c = 0; c < 3; ++c){
            const float p = wvv[a] * fc[c];
            psum[a][c] += p;
            pmax[a][c]  = fmaxf(pmax[a][c], p);
          }
      }
      #pragma unroll
      for (int m = 32; m > 0; m >>= 1){
        #pragma unroll
        for (int a = 0; a < NAGG; ++a)
          #pragma unroll
          for (int c = 0; c < 3; ++c){
            psum[a][c] += __shfl_xor(psum[a][c], m, 64);
            pmax[a][c]  = fmaxf(pmax[a][c], __shfl_xor(pmax[a][c], m, 64));
          }
      }
      if (lane == 0){
        float* gp = wsF + WSF_AGG + (((size_t)(b*2 + (l&1))*PARTS + part) * NAGG * 48);
        #pragma unroll
        for (int a = 0; a < NAGG; ++a)
          #pragma unroll
          for (int c = 0; c < 3; ++c){
            sAgg[grp][a][w3 + c]      = pmax[a][c];
            sAgg[grp][a][24 + w3 + c] = psum[a][c];
            __hip_atomic_store(&gp[a*48 + w3 + c],      pmax[a][c], __ATOMIC_RELAXED, __HIP_MEMORY_SCOPE_AGENT);
            __hip_atomic_store(&gp[a*48 + 24 + w3 + c], psum[a][c], __ATOMIC_RELAXED, __HIP_MEMORY_SCOPE_AGENT);
          }
      }
    }
    grpbar();                          // sAgg ready; all waves' ws stores drained

    // ---- post flag; hide phaseC(l-1) in the 4-way-wait window ----
    if (tl == 0)
      __hip_atomic_fetch_add(flag, 1, __ATOMIC_RELAXED, __HIP_MEMORY_SCOPE_AGENT);
    __builtin_amdgcn_sched_barrier(0);
    if (l > 0) phaseC(l - 1);          // sH still = out_{l-1}
    if (tl == 0){
      while (__hip_atomic_load(flag, __ATOMIC_RELAXED, __HIP_MEMORY_SCOPE_AGENT) < 4*l + 8)
        __builtin_amdgcn_s_sleep(2);
    }
    grpbar();

    // ---- combine 4 parts: max of maxes, mean = sum/V ----
    if (tl < 192){
      const int a = tl / 48, c = tl - a * 48;
      const size_t base = WSF_AGG + ((size_t)(b*2 + (l&1))*PARTS) * NAGG * 48;
      float v0 = __hip_atomic_load(&wsF[base + (size_t)(0*NAGG*48) + a*48 + c], __ATOMIC_RELAXED, __HIP_MEMORY_SCOPE_AGENT);
      float v1 = __hip_atomic_load(&wsF[base + (size_t)(1*NAGG*48) + a*48 + c], __ATOMIC_RELAXED, __HIP_MEMORY_SCOPE_AGENT);
      float v2 = __hip_atomic_load(&wsF[base + (size_t)(2*NAGG*48) + a*48 + c], __ATOMIC_RELAXED, __HIP_MEMORY_SCOPE_AGENT);
      float v3 = __hip_atomic_load(&wsF[base + (size_t)(3*NAGG*48) + a*48 + c], __ATOMIC_RELAXED, __HIP_MEMORY_SCOPE_AGENT);
      sAgg[grp][a][c] = (c < 24) ? fmaxf(fmaxf(v0, v1), fmaxf(v2, v3))
                                 : (v0 + v1 + v2 + v3) * (1.0f / VV);
    }
    grpbar();

    // ---- M'[a][j] -> fp16 ----
    if (tl < 128){
      const int a = tl >> 5, j = tl & 31;
      float m = Wo[(224 + a) * NFILT + j];
      #pragma unroll 8
      for (int c = 0; c < 48; ++c) m += sAgg[grp][a][c] * Wo[(32 + a*48 + c) * NFILT + j];
      sMh[grp][a*32 + j] = (f16)m;
    }
    grpbar();

    // ---- stage 3 (MFMA): o = h@WoH + w@M' + bo; h_new = bn(tanh(o)) -> sH ----
    {
      f16x8 b2f0, b2f1;
      if (frag){
        b2f0 = *(const f16x8*)&fl[(size_t)(2*64 + lane)*8];
        b2f1 = *(const f16x8*)&fl[(size_t)(3*64 + lane)*8];
      } else {
        #pragma unroll
        for (int j = 0; j < 8; ++j){
          const int k = kb*8 + j;
          b2f0[j] = (f16)Wo[k*NFILT + l16];
          b2f1[j] = (f16)Wo[k*NFILT + 16 + l16];
        }
      }
      f16x8 bmf[2];
      #pragma unroll
      for (int s = 0; s < 2; ++s)
        #pragma unroll
        for (int j = 0; j < 8; ++j)
          bmf[s][j] = (kb == 0 && j < 4) ? sMh[grp][j*32 + s*16 + l16] : (f16)0.f;

      float boc[2], bmc[2], scc[2], bec[2];
      #pragma unroll
      for (int s = 0; s < 2; ++s){
        const int cc = s*16 + l16;
        boc[s] = bo[cc];
        bmc[s] = bm[cc];
        scc[s] = g_[cc] * rsqrtf(bv[cc] + BN_EPS);
        bec[s] = be[cc];
      }

      #pragma unroll
      for (int i = 0; i < 4; ++i){
        const int tb = wv*64 + i*16;
        const f16x8 ahi = *(const f16x8*)&sHhi[grp][(tb + l16)*SHS + kb*8];
        const f16x8 alo = *(const f16x8*)&sHlo[grp][(tb + l16)*SHS + kb*8];
        f16x8 wa;
        #pragma unroll
        for (int j = 0; j < 8; ++j) wa[j] = (f16)0.f;
        {
          const f32x4 wvv = *(const f32x4*)&sW[grp][(tb + l16)*4];
          if (kb == 0){
            wa[0] = (f16)wvv[0]; wa[1] = (f16)wvv[1];
            wa[2] = (f16)wvv[2]; wa[3] = (f16)wvv[3];
          }
        }
        #pragma unroll
        for (int s = 0; s < 2; ++s){
          f32x4 o = (f32x4){0.f, 0.f, 0.f, 0.f};
          o = MFMA(ahi, (s ? b2f1 : b2f0), o);
          o = MFMA(alo, (s ? b2f1 : b2f0), o);
          o = MFMA(wa,  bmf[s], o);
          #pragma unroll
          for (int q = 0; q < 4; ++q){
            const float th = fast_tanh(o[q] + boc[s]);
            const float hn = (th - bmc[s]) * scc[s] + bec[s];
            const f16 hh = (f16)hn;
            const int idx = (tb + kb*4 + q)*SHS + s*16 + l16;
            sHhi[grp][idx] = hh;
            sHlo[grp][idx] = (f16)(hn - (float)hh);
          }
        }
      }
    }
    // stage3 wrote only own-wave rows; next stage1/phaseC read own-wave rows.
    asm volatile("s_waitcnt lgkmcnt(0)" ::: "memory");
  }

  phaseC(NBLK - 1);

  // ---------------- head: out = relu(relu(acc) @ W_o1 + b_o1) ----------------
  {
    float w1c[3][3];
    #pragma unroll
    for (int s = 0; s < 3; ++s)
      #pragma unroll
      for (int m = 0; m < 3; ++m) w1c[s][m] = W_o1[(s*16 + l16)*3 + m];
    const float bo1_0 = b_o1[0], bo1_1 = b_o1[1], bo1_2 = b_o1[2];

    #pragma unroll
    for (int i = 0; i < 4; ++i){
      const int tb = wv*64 + i*16;
      float p[4][3];
      #pragma unroll
      for (int q = 0; q < 4; ++q){ p[q][0]=0.f; p[q][1]=0.f; p[q][2]=0.f; }
      #pragma unroll
      for (int s = 0; s < 3; ++s)
        #pragma unroll
        for (int q = 0; q < 4; ++q){
          const float r_ = fmaxf(acc[i][s][q], 0.f);
          p[q][0] += r_ * w1c[s][0];
          p[q][1] += r_ * w1c[s][1];
          p[q][2] += r_ * w1c[s][2];
        }
      #pragma unroll
      for (int m = 1; m <= 8; m <<= 1)
        #pragma unroll
        for (int q = 0; q < 4; ++q){
          p[q][0] += __shfl_xor(p[q][0], m, 64);
          p[q][1] += __shfl_xor(p[q][1], m, 64);
          p[q][2] += __shfl_xor(p[q][2], m, 64);
        }
      if (l16 < 3){
        const float bo1v = (l16 == 0) ? bo1_0 : ((l16 == 1) ? bo1_1 : bo1_2);
        #pragma unroll
        for (int q = 0; q < 4; ++q){
          const float vv = (l16 == 0) ? p[q][0] : ((l16 == 1) ? p[q][1] : p[q][2]);
          out[((size_t)b*VV + part*PV + tb + kb*4 + q)*3 + l16] = fmaxf(vv + bo1v, 0.f);
        }
      }
    }
  }
}

extern "C" void kernel_launch(void* const* d_in, const int* in_sizes, int n_in,
                              void* d_out, int out_size, void* d_ws, size_t ws_size,
                              hipStream_t stream) {
  const float* x      = (const float*)d_in[0];
  const float* bn0_g  = (const float*)d_in[1];
  const float* bn0_b  = (const float*)d_in[2];
  const float* bn0_m  = (const float*)d_in[3];
  const float* bn0_v  = (const float*)d_in[4];
  const float* W_in   = (const float*)d_in[5];
  const float* b_in   = (const float*)d_in[6];
  const float* W_flr  = (const float*)d_in[7];
  const float* b_flr  = (const float*)d_in[8];
  const float* W_s    = (const float*)d_in[9];
  const float* b_s    = (const float*)d_in[10];
  const float* W_out  = (const float*)d_in[11];
  const float* b_out  = (const float*)d_in[12];
  const float* bn_g   = (const float*)d_in[13];
  const float* bn_b   = (const float*)d_in[14];
  const float* bn_m   = (const float*)d_in[15];
  const float* bn_v   = (const float*)d_in[16];
  const float* W_o0   = (const float*)d_in[17];
  const float* b_o0   = (const float*)d_in[18];
  const float* W_o1   = (const float*)d_in[19];
  const float* b_o1   = (const float*)d_in[20];

  float* wsF = (float*)d_ws;
  const size_t needed = (size_t)WSF_END * 4 + (size_t)NFRAG * 2;
  _Float16* frag = (ws_size >= needed) ? (_Float16*)(wsF + WSF_END) : nullptr;

  hipMemsetAsync(d_ws, 0, BB * sizeof(int), stream);

  if (frag)
    garnet_prep<<<dim3((NFRAG + 255) / 256), dim3(256), 0, stream>>>(
        W_flr, W_s, W_out, W_o0, frag);

  garnet_fused<<<dim3(BB * 2), dim3(TPB), 0, stream>>>(
      x, bn0_g, bn0_b, bn0_m, bn0_v, W_in, b_in,
      W_flr, b_flr, W_s, b_s, W_out, b_out,
      bn_g, bn_b, bn_m, bn_v, W_o0, b_o0, W_o1, b_o1,
      (int*)d_ws, wsF, frag, (float*)d_out);
}

// Round 21
// 169.399 us; speedup vs baseline: 1.1934x; 1.1934x over previous
//
#include <hip/hip_runtime.h>
#include <math.h>

#define NBLK  11
#define NAGG  4
#define NFILT 32
#define NPROP 20
#define BB    128
#define VV    1024
#define HV    512
#define FIN   10
#define TPB   512
#define BN_EPS 1e-3f
#define SHS   40    // sH row stride in halves: 80 B, 16B-aligned
#define SFTS  520   // sFT col stride in halves (1040 B)

#define WSF_MEAN 128
#define WSF_AGG  (WSF_MEAN + BB*2*FIN)                  // 2688
#define WSF_FRAG (WSF_AGG + (BB*2*2) * NAGG * 48)      // 100992 floats = 404 KB
#define NFRAG    (NBLK*7*64*8)                          // 39424 f16 = 79 KB

typedef _Float16 f16;
typedef f16   f16x4 __attribute__((ext_vector_type(4)));
typedef f16   f16x8 __attribute__((ext_vector_type(8)));
typedef float f32x4 __attribute__((ext_vector_type(4)));

__device__ __forceinline__ f32x4 MFMA(f16x8 a, f16x8 b, f32x4 c){
  return __builtin_amdgcn_mfma_f32_16x16x32_f16(a, b, c, 0, 0, 0);
}

__device__ __forceinline__ float fast_tanh(float x){
  float a = fabsf(x);
  float e = __expf(-2.0f * a);
  float r = (1.0f - e) / (1.0f + e);
  return copysignf(r, x);
}

// prep: f16 B-fragment table (79 KB), r15-proven.
extern "C" __global__ void garnet_prep(
    const float* __restrict__ W_flr, const float* __restrict__ W_s,
    const float* __restrict__ W_out, const float* __restrict__ W_o0,
    f16* __restrict__ frag)
{
  const int idx = blockIdx.x * blockDim.x + threadIdx.x;
  if (idx >= NFRAG) return;
  const int j    = idx & 7;
  const int lane = (idx >> 3) & 63;
  const int rest = idx >> 9;
  const int set  = rest % 7;
  const int l    = rest / 7;
  const int l16  = lane & 15, kb = lane >> 4, k = kb*8 + j;
  float val = 0.f;
  if (set < 2){
    const int n = set*16 + l16;
    if (set == 0) val = W_flr[l*NFILT*NPROP + k*NPROP + n];
    else          val = (n < 20) ? W_flr[l*NFILT*NPROP + k*NPROP + n]
                       : (n < 24 ? W_s[l*NFILT*NAGG + k*NAGG + (n-20)] : 0.f);
  } else if (set < 4){
    const int s = set - 2;
    val = W_out[l*228*NFILT + k*NFILT + s*16 + l16];
  } else {
    const int s = set - 4;
    val = W_o0[((size_t)l*NFILT + k)*48 + s*16 + l16];
  }
  frag[idx] = (f16)val;
}

// r18 base (164 us best) + combine fused into M' (one less barrier/layer):
// combined agg is consumed ONLY by M', so compute it inline there.
// Single-f16 h; w fp32 in sW; stage2 cols>=20 read w from sW (r18 bugfix kept).
// MFMA 16x16x32 frags (m89-verified): A[row=lane&15][k=8*(lane>>4)+j],
// B[k][col=lane&15], C[row=4*(lane>>4)+q][col=lane&15].
extern "C" __global__ __launch_bounds__(TPB)
void garnet_fused(
    const float* __restrict__ x,
    const float* __restrict__ bn0_g, const float* __restrict__ bn0_b,
    const float* __restrict__ bn0_m, const float* __restrict__ bn0_v,
    const float* __restrict__ W_in,  const float* __restrict__ b_in,
    const float* __restrict__ W_flr, const float* __restrict__ b_flr,
    const float* __restrict__ W_s,   const float* __restrict__ b_s,
    const float* __restrict__ W_out, const float* __restrict__ b_out,
    const float* __restrict__ bn_g,  const float* __restrict__ bn_b,
    const float* __restrict__ bn_m,  const float* __restrict__ bn_v,
    const float* __restrict__ W_o0,  const float* __restrict__ b_o0,
    const float* __restrict__ W_o1,  const float* __restrict__ b_o1,
    int* __restrict__ wsFlag, float* __restrict__ wsF,
    const f16* __restrict__ frag,
    float* __restrict__ out)
{
  const int wg   = blockIdx.x;
  const int b    = wg & (BB - 1);
  const int half = wg >> 7;
  const int t    = threadIdx.x;
  const int lane = t & 63;
  const int wave = t >> 6;
  const int v    = half * HV + t;
  const int l16  = lane & 15;
  const int kb   = lane >> 4;

  __shared__ __align__(16) f16 sH[HV * SHS];       // 40 KB, h as f16
  __shared__ __align__(16) f16 sFT[20 * SFTS];     // 20.3 KB, f cols transposed
  __shared__ __align__(16) float sW[HV * 4];       // 8 KB, w fp32 [row][a]
  __shared__ f16   sMh[4 * 32];
  __shared__ float sAgg[NAGG][48];
  __shared__ float sRed[8][FIN];
  __shared__ float sMean[FIN];

  int* flag = wsFlag + b;

  f32x4 acc[4][3];

  // phaseC(lc): acc += out_lc @ W_o0_slice(lc); reads sH (= out_lc) only.
  auto phaseC = [&](int lc){
    f16x8 b3f[3];
    if (frag){
      const f16* flC = frag + (size_t)lc * 7 * 64 * 8;
      #pragma unroll
      for (int s = 0; s < 3; ++s)
        b3f[s] = *(const f16x8*)&flC[(size_t)((4 + s)*64 + lane)*8];
    } else {
      const float* Wo0l = W_o0 + (size_t)lc * NFILT * 48;
      #pragma unroll
      for (int s = 0; s < 3; ++s)
        #pragma unroll
        for (int j = 0; j < 8; ++j)
          b3f[s][j] = (f16)Wo0l[(kb*8 + j)*48 + s*16 + l16];
    }
    #pragma unroll
    for (int i = 0; i < 4; ++i){
      const int tb = wave*64 + i*16;
      const f16x8 a_ = *(const f16x8*)&sH[(tb + l16)*SHS + kb*8];
      #pragma unroll
      for (int s = 0; s < 3; ++s)
        acc[i][s] = MFMA(a_, b3f[s], acc[i][s]);
    }
  };

  // ---------------- phase 0: mean over V (cross-half) + input dense ----------------
  {
    float h[NFILT];
    float xv[FIN];
    const float* xp = x + ((size_t)b * VV + v) * FIN;
    #pragma unroll
    for (int c = 0; c < FIN; ++c) xv[c] = xp[c];

    float ps[FIN];
    #pragma unroll
    for (int c = 0; c < FIN; ++c) ps[c] = xv[c];
    #pragma unroll
    for (int m = 32; m > 0; m >>= 1){
      #pragma unroll
      for (int c = 0; c < FIN; ++c) ps[c] += __shfl_xor(ps[c], m, 64);
    }
    if (lane == 0){
      #pragma unroll
      for (int c = 0; c < FIN; ++c) sRed[wave][c] = ps[c];
    }
    __syncthreads();
    if (t < FIN){
      float s = 0.f;
      #pragma unroll
      for (int wv = 0; wv < 8; ++wv) s += sRed[wv][t];
      sRed[0][t] = s;
      __hip_atomic_store(&wsF[WSF_MEAN + (b*2 + half)*FIN + t], s,
                         __ATOMIC_RELAXED, __HIP_MEMORY_SCOPE_AGENT);
    }
    __syncthreads();
    if (t == 0){
      asm volatile("s_waitcnt vmcnt(0)" ::: "memory");
      __hip_atomic_fetch_add(flag, 1, __ATOMIC_RELAXED, __HIP_MEMORY_SCOPE_AGENT);
      while (__hip_atomic_load(flag, __ATOMIC_RELAXED, __HIP_MEMORY_SCOPE_AGENT) < 2)
        __builtin_amdgcn_s_sleep(2);
    }
    __syncthreads();
    if (t < FIN){
      float theirs = __hip_atomic_load(&wsF[WSF_MEAN + (b*2 + (half^1))*FIN + t],
                                       __ATOMIC_RELAXED, __HIP_MEMORY_SCOPE_AGENT);
      sMean[t] = (sRed[0][t] + theirs) * (1.0f / VV);
    }
    __syncthreads();

    float o[NFILT];
    #pragma unroll
    for (int j = 0; j < NFILT; ++j) o[j] = b_in[j];
    #pragma unroll
    for (int c = 0; c < FIN; ++c){
      const float zx = (xv[c]    - bn0_m[c])     * (bn0_g[c]     * rsqrtf(bn0_v[c]     + BN_EPS)) + bn0_b[c];
      const float zm = (sMean[c] - bn0_m[FIN+c]) * (bn0_g[FIN+c] * rsqrtf(bn0_v[FIN+c] + BN_EPS)) + bn0_b[FIN+c];
      #pragma unroll
      for (int j = 0; j < NFILT; ++j)
        o[j] += zx * W_in[c*NFILT + j] + zm * W_in[(FIN+c)*NFILT + j];
    }
    #pragma unroll
    for (int j = 0; j < NFILT; ++j) h[j] = fast_tanh(o[j]);

    #pragma unroll
    for (int c = 0; c < 4; ++c){
      f16x8 hh;
      #pragma unroll
      for (int j = 0; j < 8; ++j) hh[j] = (f16)h[c*8 + j];
      *(f16x8*)&sH[t*SHS + c*8] = hh;
    }
  }
  __syncthreads();

  #pragma unroll
  for (int s = 0; s < 3; ++s){
    const float a0 = b_o0[s*16 + l16];
    #pragma unroll
    for (int i = 0; i < 4; ++i) acc[i][s] = (f32x4){a0, a0, a0, a0};
  }

  for (int l = 0; l < NBLK; ++l){
    const float* Wf = W_flr + l * NFILT * NPROP;
    const float* bf = b_flr + l * NPROP;
    const float* Ws = W_s   + l * NFILT * NAGG;
    const float* bs = b_s   + l * NAGG;
    const float* Wo = W_out + l * 228 * NFILT;
    const float* bo = b_out + l * NFILT;
    const float* g_ = bn_g  + l * NFILT;
    const float* be = bn_b  + l * NFILT;
    const float* bm = bn_m  + l * NFILT;
    const float* bv = bn_v  + l * NFILT;
    const f16*  fl  = frag + (size_t)l * 7 * 64 * 8;

    // ---- stage 1 (MFMA): feat = h @ [Wf|Ws]; f -> sFT f16, w = exp(-|d|) -> sW f32 ----
    {
      f16x8 b1f0, b1f1;
      if (frag){
        b1f0 = *(const f16x8*)&fl[(size_t)(0*64 + lane)*8];
        b1f1 = *(const f16x8*)&fl[(size_t)(1*64 + lane)*8];
      } else {
        #pragma unroll
        for (int j = 0; j < 8; ++j){
          const int k = kb*8 + j;
          b1f0[j] = (f16)Wf[k*NPROP + l16];
          const int n = 16 + l16;
          b1f1[j] = (f16)((n < 20) ? Wf[k*NPROP + n] : (n < 24 ? Ws[k*NAGG + (n-20)] : 0.f));
        }
      }
      const float bias0 = bf[l16];
      const int  c1 = 16 + l16;
      const float bias1 = (c1 < 20) ? bf[c1] : (c1 < 24 ? bs[c1-20] : 0.f);

      #pragma unroll
      for (int i = 0; i < 4; ++i){
        const int tb = wave*64 + i*16;
        const f16x8 a_ = *(const f16x8*)&sH[(tb + l16)*SHS + kb*8];
        f32x4 c0 = (f32x4){bias0, bias0, bias0, bias0};
        c0 = MFMA(a_, b1f0, c0);
        f16x4 s0;
        #pragma unroll
        for (int q = 0; q < 4; ++q) s0[q] = (f16)c0[q];
        *(f16x4*)&sFT[l16*SFTS + tb + kb*4] = s0;

        f32x4 c1v = (f32x4){bias1, bias1, bias1, bias1};
        c1v = MFMA(a_, b1f1, c1v);
        if (l16 < 4){
          f16x4 s1;
          #pragma unroll
          for (int q = 0; q < 4; ++q) s1[q] = (f16)c1v[q];
          *(f16x4*)&sFT[(16 + l16)*SFTS + tb + kb*4] = s1;
        } else if (l16 < 8){
          #pragma unroll
          for (int q = 0; q < 4; ++q)
            sW[(tb + kb*4 + q)*4 + (l16 - 4)] = __expf(-fabsf(c1v[q]));
        }
      }
    }
    __syncthreads();

    // ---- stage 2: partial max/sum over 512 rows; wave owns cols 3w..3w+2 ----
    // cols 0..19 = f (sFT), cols 20..23 = w (sW)
    {
      const int w3 = wave * 3;
      float psum[NAGG][3], pmax[NAGG][3];
      #pragma unroll
      for (int a = 0; a < NAGG; ++a)
        #pragma unroll
        for (int c = 0; c < 3; ++c){ psum[a][c] = 0.f; pmax[a][c] = -INFINITY; }
      for (int i = 0; i < 8; ++i){
        const int row = i * 64 + lane;
        const f32x4 wv = *(const f32x4*)&sW[row*4];
        float fc[3];
        #pragma unroll
        for (int c = 0; c < 3; ++c){
          const int col = w3 + c;
          fc[c] = (col < 20) ? (float)sFT[col*SFTS + row] : wv[col - 20];
        }
        #pragma unroll
        for (int a = 0; a < NAGG; ++a)
          #pragma unroll
          for (int c = 0; c < 3; ++c){
            const float p = wv[a] * fc[c];
            psum[a][c] += p;
            pmax[a][c]  = fmaxf(pmax[a][c], p);
          }
      }
      #pragma unroll
      for (int m = 32; m > 0; m >>= 1){
        #pragma unroll
        for (int a = 0; a < NAGG; ++a)
          #pragma unroll
          for (int c = 0; c < 3; ++c){
            psum[a][c] += __shfl_xor(psum[a][c], m, 64);
            pmax[a][c]  = fmaxf(pmax[a][c], __shfl_xor(pmax[a][c], m, 64));
          }
      }
      if (lane == 0){
        float* gp = wsF + WSF_AGG + (((size_t)(b*2 + (l&1))*2 + half) * NAGG * 48);
        #pragma unroll
        for (int a = 0; a < NAGG; ++a)
          #pragma unroll
          for (int c = 0; c < 3; ++c){
            sAgg[a][w3 + c]      = pmax[a][c];      // local partial (mine)
            sAgg[a][24 + w3 + c] = psum[a][c];
            __hip_atomic_store(&gp[a*48 + w3 + c],      pmax[a][c], __ATOMIC_RELAXED, __HIP_MEMORY_SCOPE_AGENT);
            __hip_atomic_store(&gp[a*48 + 24 + w3 + c], psum[a][c], __ATOMIC_RELAXED, __HIP_MEMORY_SCOPE_AGENT);
          }
      }
    }
    __syncthreads();

    // ---- post flag; hide phaseC(l-1) in the partner-wait window ----
    if (t == 0){
      asm volatile("s_waitcnt vmcnt(0)" ::: "memory");
      __hip_atomic_fetch_add(flag, 1, __ATOMIC_RELAXED, __HIP_MEMORY_SCOPE_AGENT);
    }
    __builtin_amdgcn_sched_barrier(0);
    if (l > 0) phaseC(l - 1);            // sH still = out_{l-1}
    if (t == 0){
      while (__hip_atomic_load(flag, __ATOMIC_RELAXED, __HIP_MEMORY_SCOPE_AGENT) < 2*l + 4)
        __builtin_amdgcn_s_sleep(2);
    }
    __syncthreads();

    // ---- M' with FUSED combine: comb = max/mean(mine, partner); only M' needs it ----
    if (t < 128){
      const int a = t >> 5, j = t & 31;
      const float* pp = wsF + WSF_AGG + (((size_t)(b*2 + (l&1))*2 + (half^1)) * NAGG * 48);
      float m = Wo[(224 + a) * NFILT + j];
      #pragma unroll 8
      for (int c = 0; c < 48; ++c){
        const float mine   = sAgg[a][c];
        const float theirs = __hip_atomic_load(&pp[a*48 + c], __ATOMIC_RELAXED, __HIP_MEMORY_SCOPE_AGENT);
        const float comb = (c < 24) ? fmaxf(mine, theirs) : (mine + theirs) * (1.0f / VV);
        m += comb * Wo[(32 + a*48 + c) * NFILT + j];
      }
      sMh[a*32 + j] = (f16)m;
    }
    __syncthreads();

    // ---- stage 3 (MFMA): o = h@WoH + w@M' + bo; h_new = bn(tanh(o)) -> sH ----
    {
      f16x8 b2f0, b2f1;
      if (frag){
        b2f0 = *(const f16x8*)&fl[(size_t)(2*64 + lane)*8];
        b2f1 = *(const f16x8*)&fl[(size_t)(3*64 + lane)*8];
      } else {
        #pragma unroll
        for (int j = 0; j < 8; ++j){
          const int k = kb*8 + j;
          b2f0[j] = (f16)Wo[k*NFILT + l16];
          b2f1[j] = (f16)Wo[k*NFILT + 16 + l16];
        }
      }
      f16x8 bmf[2];
      #pragma unroll
      for (int s = 0; s < 2; ++s)
        #pragma unroll
        for (int j = 0; j < 8; ++j)
          bmf[s][j] = (kb == 0 && j < 4) ? sMh[j*32 + s*16 + l16] : (f16)0.f;

      float boc[2], bmc[2], scc[2], bec[2];
      #pragma unroll
      for (int s = 0; s < 2; ++s){
        const int cc = s*16 + l16;
        boc[s] = bo[cc];
        bmc[s] = bm[cc];
        scc[s] = g_[cc] * rsqrtf(bv[cc] + BN_EPS);
        bec[s] = be[cc];
      }

      #pragma unroll
      for (int i = 0; i < 4; ++i){
        const int tb = wave*64 + i*16;
        const f16x8 a_ = *(const f16x8*)&sH[(tb + l16)*SHS + kb*8];
        f16x8 wa;
        #pragma unroll
        for (int j = 0; j < 8; ++j) wa[j] = (f16)0.f;
        {
          const f32x4 wv = *(const f32x4*)&sW[(tb + l16)*4];
          if (kb == 0){
            wa[0] = (f16)wv[0]; wa[1] = (f16)wv[1];
            wa[2] = (f16)wv[2]; wa[3] = (f16)wv[3];
          }
        }
        #pragma unroll
        for (int s = 0; s < 2; ++s){
          f32x4 o = (f32x4){0.f, 0.f, 0.f, 0.f};
          o = MFMA(a_, (s ? b2f1 : b2f0), o);
          o = MFMA(wa, bmf[s], o);
          #pragma unroll
          for (int q = 0; q < 4; ++q){
            const float th = fast_tanh(o[q] + boc[s]);
            const float hn = (th - bmc[s]) * scc[s] + bec[s];
            sH[(tb + kb*4 + q)*SHS + s*16 + l16] = (f16)hn;
          }
        }
      }
    }
    asm volatile("s_waitcnt lgkmcnt(0)" ::: "memory");
  }

  phaseC(NBLK - 1);

  // ---------------- head: out = relu(relu(acc) @ W_o1 + b_o1) ----------------
  {
    float w1c[3][3];
    #pragma unroll
    for (int s = 0; s < 3; ++s)
      #pragma unroll
      for (int m = 0; m < 3; ++m) w1c[s][m] = W_o1[(s*16 + l16)*3 + m];
    const float bo1_0 = b_o1[0], bo1_1 = b_o1[1], bo1_2 = b_o1[2];

    #pragma unroll
    for (int i = 0; i < 4; ++i){
      const int tb = wave*64 + i*16;
      float p[4][3];
      #pragma unroll
      for (int q = 0; q < 4; ++q){ p[q][0]=0.f; p[q][1]=0.f; p[q][2]=0.f; }
      #pragma unroll
      for (int s = 0; s < 3; ++s)
        #pragma unroll
        for (int q = 0; q < 4; ++q){
          const float r_ = fmaxf(acc[i][s][q], 0.f);
          p[q][0] += r_ * w1c[s][0];
          p[q][1] += r_ * w1c[s][1];
          p[q][2] += r_ * w1c[s][2];
        }
      #pragma unroll
      for (int m = 1; m <= 8; m <<= 1)
        #pragma unroll
        for (int q = 0; q < 4; ++q){
          p[q][0] += __shfl_xor(p[q][0], m, 64);
          p[q][1] += __shfl_xor(p[q][1], m, 64);
          p[q][2] += __shfl_xor(p[q][2], m, 64);
        }
      if (l16 < 3){
        const float bo1v = (l16 == 0) ? bo1_0 : ((l16 == 1) ? bo1_1 : bo1_2);
        #pragma unroll
        for (int q = 0; q < 4; ++q){
          const float vv = (l16 == 0) ? p[q][0] : ((l16 == 1) ? p[q][1] : p[q][2]);
          out[((size_t)b*VV + half*HV + tb + kb*4 + q)*3 + l16] = fmaxf(vv + bo1v, 0.f);
        }
      }
    }
  }
}

extern "C" void kernel_launch(void* const* d_in, const int* in_sizes, int n_in,
                              void* d_out, int out_size, void* d_ws, size_t ws_size,
                              hipStream_t stream) {
  const float* x      = (const float*)d_in[0];
  const float* bn0_g  = (const float*)d_in[1];
  const float* bn0_b  = (const float*)d_in[2];
  const float* bn0_m  = (const float*)d_in[3];
  const float* bn0_v  = (const float*)d_in[4];
  const float* W_in   = (const float*)d_in[5];
  const float* b_in   = (const float*)d_in[6];
  const float* W_flr  = (const float*)d_in[7];
  const float* b_flr  = (const float*)d_in[8];
  const float* W_s    = (const float*)d_in[9];
  const float* b_s    = (const float*)d_in[10];
  const float* W_out  = (const float*)d_in[11];
  const float* b_out  = (const float*)d_in[12];
  const float* bn_g   = (const float*)d_in[13];
  const float* bn_b   = (const float*)d_in[14];
  const float* bn_m   = (const float*)d_in[15];
  const float* bn_v   = (const float*)d_in[16];
  const float* W_o0   = (const float*)d_in[17];
  const float* b_o0   = (const float*)d_in[18];
  const float* W_o1   = (const float*)d_in[19];
  const float* b_o1   = (const float*)d_in[20];

  float* wsF = (float*)d_ws;
  const size_t needed = (size_t)WSF_FRAG * 4 + (size_t)NFRAG * 2;
  _Float16* frag = (ws_size >= needed) ? (_Float16*)(wsF + WSF_FRAG) : nullptr;

  hipMemsetAsync(d_ws, 0, BB * sizeof(int), stream);

  if (frag)
    garnet_prep<<<dim3((NFRAG + 255) / 256), dim3(256), 0, stream>>>(
        W_flr, W_s, W_out, W_o0, frag);

  garnet_fused<<<dim3(BB * 2), dim3(TPB), 0, stream>>>(
      x, bn0_g, bn0_b, bn0_m, bn0_v, W_in, b_in,
      W_flr, b_flr, W_s, b_s, W_out, b_out,
      bn_g, bn_b, bn_m, bn_v, W_o0, b_o0, W_o1, b_o1,
      (int*)d_ws, wsF, frag, (float*)d_out);
}

// Round 22
// 163.962 us; speedup vs baseline: 1.2329x; 1.0332x over previous
//
#include <hip/hip_runtime.h>
#include <math.h>

#define NBLK  11
#define NAGG  4
#define NFILT 32
#define NPROP 20
#define BB    128
#define VV    1024
#define HV    512
#define FIN   10
#define TPB   512
#define BN_EPS 1e-3f
#define SHS   40    // sH row stride in halves: 80 B, 16B-aligned
#define SFTS  520   // sFT col stride in halves (1040 B)

#define WSF_MEAN 128
#define WSF_AGG  (WSF_MEAN + BB*2*FIN)                  // 2688
#define WSF_FRAG (WSF_AGG + (BB*2*2) * NAGG * 48)      // 100992 floats = 404 KB
#define NFRAG    (NBLK*7*64*8)                          // 39424 f16 = 79 KB

typedef _Float16 f16;
typedef f16   f16x4 __attribute__((ext_vector_type(4)));
typedef f16   f16x8 __attribute__((ext_vector_type(8)));
typedef float f32x4 __attribute__((ext_vector_type(4)));

__device__ __forceinline__ f32x4 MFMA(f16x8 a, f16x8 b, f32x4 c){
  return __builtin_amdgcn_mfma_f32_16x16x32_f16(a, b, c, 0, 0, 0);
}

__device__ __forceinline__ float fast_tanh(float x){
  float a = fabsf(x);
  float e = __expf(-2.0f * a);
  float r = (1.0f - e) / (1.0f + e);
  return copysignf(r, x);
}

// prep: f16 B-fragment table (79 KB), r15-proven.
extern "C" __global__ void garnet_prep(
    const float* __restrict__ W_flr, const float* __restrict__ W_s,
    const float* __restrict__ W_out, const float* __restrict__ W_o0,
    f16* __restrict__ frag)
{
  const int idx = blockIdx.x * blockDim.x + threadIdx.x;
  if (idx >= NFRAG) return;
  const int j    = idx & 7;
  const int lane = (idx >> 3) & 63;
  const int rest = idx >> 9;
  const int set  = rest % 7;
  const int l    = rest / 7;
  const int l16  = lane & 15, kb = lane >> 4, k = kb*8 + j;
  float val = 0.f;
  if (set < 2){
    const int n = set*16 + l16;
    if (set == 0) val = W_flr[l*NFILT*NPROP + k*NPROP + n];
    else          val = (n < 20) ? W_flr[l*NFILT*NPROP + k*NPROP + n]
                       : (n < 24 ? W_s[l*NFILT*NAGG + k*NAGG + (n-20)] : 0.f);
  } else if (set < 4){
    const int s = set - 2;
    val = W_out[l*228*NFILT + k*NFILT + s*16 + l16];
  } else {
    const int s = set - 4;
    val = W_o0[((size_t)l*NFILT + k)*48 + s*16 + l16];
  }
  frag[idx] = (f16)val;
}

// r18 exact (best measured: 164.1 us, absmax 4.88e-3):
// single-f16 h (MFMAs 64->36/wave/layer); w fp32 in sW; stage2 cols>=20 from sW;
// separate combine step; phaseC hidden in the pair-sync spin window;
// relaxed cross-WG sync (r13-proven); frag table guarded by ws_size (r14 lesson).
// MFMA 16x16x32 frags (m89-verified): A[row=lane&15][k=8*(lane>>4)+j],
// B[k][col=lane&15], C[row=4*(lane>>4)+q][col=lane&15].
extern "C" __global__ __launch_bounds__(TPB)
void garnet_fused(
    const float* __restrict__ x,
    const float* __restrict__ bn0_g, const float* __restrict__ bn0_b,
    const float* __restrict__ bn0_m, const float* __restrict__ bn0_v,
    const float* __restrict__ W_in,  const float* __restrict__ b_in,
    const float* __restrict__ W_flr, const float* __restrict__ b_flr,
    const float* __restrict__ W_s,   const float* __restrict__ b_s,
    const float* __restrict__ W_out, const float* __restrict__ b_out,
    const float* __restrict__ bn_g,  const float* __restrict__ bn_b,
    const float* __restrict__ bn_m,  const float* __restrict__ bn_v,
    const float* __restrict__ W_o0,  const float* __restrict__ b_o0,
    const float* __restrict__ W_o1,  const float* __restrict__ b_o1,
    int* __restrict__ wsFlag, float* __restrict__ wsF,
    const f16* __restrict__ frag,
    float* __restrict__ out)
{
  const int wg   = blockIdx.x;
  const int b    = wg & (BB - 1);
  const int half = wg >> 7;
  const int t    = threadIdx.x;
  const int lane = t & 63;
  const int wave = t >> 6;
  const int v    = half * HV + t;
  const int l16  = lane & 15;
  const int kb   = lane >> 4;

  __shared__ __align__(16) f16 sH[HV * SHS];       // 40 KB, h as f16
  __shared__ __align__(16) f16 sFT[20 * SFTS];     // 20.3 KB, f cols transposed
  __shared__ __align__(16) float sW[HV * 4];       // 8 KB, w fp32 [row][a]
  __shared__ f16   sMh[4 * 32];
  __shared__ float sAgg[NAGG][48];
  __shared__ float sRed[8][FIN];
  __shared__ float sMean[FIN];

  int* flag = wsFlag + b;

  f32x4 acc[4][3];

  // phaseC(lc): acc += out_lc @ W_o0_slice(lc); reads sH (= out_lc) only.
  auto phaseC = [&](int lc){
    f16x8 b3f[3];
    if (frag){
      const f16* flC = frag + (size_t)lc * 7 * 64 * 8;
      #pragma unroll
      for (int s = 0; s < 3; ++s)
        b3f[s] = *(const f16x8*)&flC[(size_t)((4 + s)*64 + lane)*8];
    } else {
      const float* Wo0l = W_o0 + (size_t)lc * NFILT * 48;
      #pragma unroll
      for (int s = 0; s < 3; ++s)
        #pragma unroll
        for (int j = 0; j < 8; ++j)
          b3f[s][j] = (f16)Wo0l[(kb*8 + j)*48 + s*16 + l16];
    }
    #pragma unroll
    for (int i = 0; i < 4; ++i){
      const int tb = wave*64 + i*16;
      const f16x8 a_ = *(const f16x8*)&sH[(tb + l16)*SHS + kb*8];
      #pragma unroll
      for (int s = 0; s < 3; ++s)
        acc[i][s] = MFMA(a_, b3f[s], acc[i][s]);
    }
  };

  // ---------------- phase 0: mean over V (cross-half) + input dense ----------------
  {
    float h[NFILT];
    float xv[FIN];
    const float* xp = x + ((size_t)b * VV + v) * FIN;
    #pragma unroll
    for (int c = 0; c < FIN; ++c) xv[c] = xp[c];

    float ps[FIN];
    #pragma unroll
    for (int c = 0; c < FIN; ++c) ps[c] = xv[c];
    #pragma unroll
    for (int m = 32; m > 0; m >>= 1){
      #pragma unroll
      for (int c = 0; c < FIN; ++c) ps[c] += __shfl_xor(ps[c], m, 64);
    }
    if (lane == 0){
      #pragma unroll
      for (int c = 0; c < FIN; ++c) sRed[wave][c] = ps[c];
    }
    __syncthreads();
    if (t < FIN){
      float s = 0.f;
      #pragma unroll
      for (int wv = 0; wv < 8; ++wv) s += sRed[wv][t];
      sRed[0][t] = s;
      __hip_atomic_store(&wsF[WSF_MEAN + (b*2 + half)*FIN + t], s,
                         __ATOMIC_RELAXED, __HIP_MEMORY_SCOPE_AGENT);
    }
    __syncthreads();
    if (t == 0){
      asm volatile("s_waitcnt vmcnt(0)" ::: "memory");
      __hip_atomic_fetch_add(flag, 1, __ATOMIC_RELAXED, __HIP_MEMORY_SCOPE_AGENT);
      while (__hip_atomic_load(flag, __ATOMIC_RELAXED, __HIP_MEMORY_SCOPE_AGENT) < 2)
        __builtin_amdgcn_s_sleep(2);
    }
    __syncthreads();
    if (t < FIN){
      float theirs = __hip_atomic_load(&wsF[WSF_MEAN + (b*2 + (half^1))*FIN + t],
                                       __ATOMIC_RELAXED, __HIP_MEMORY_SCOPE_AGENT);
      sMean[t] = (sRed[0][t] + theirs) * (1.0f / VV);
    }
    __syncthreads();

    float o[NFILT];
    #pragma unroll
    for (int j = 0; j < NFILT; ++j) o[j] = b_in[j];
    #pragma unroll
    for (int c = 0; c < FIN; ++c){
      const float zx = (xv[c]    - bn0_m[c])     * (bn0_g[c]     * rsqrtf(bn0_v[c]     + BN_EPS)) + bn0_b[c];
      const float zm = (sMean[c] - bn0_m[FIN+c]) * (bn0_g[FIN+c] * rsqrtf(bn0_v[FIN+c] + BN_EPS)) + bn0_b[FIN+c];
      #pragma unroll
      for (int j = 0; j < NFILT; ++j)
        o[j] += zx * W_in[c*NFILT + j] + zm * W_in[(FIN+c)*NFILT + j];
    }
    #pragma unroll
    for (int j = 0; j < NFILT; ++j) h[j] = fast_tanh(o[j]);

    #pragma unroll
    for (int c = 0; c < 4; ++c){
      f16x8 hh;
      #pragma unroll
      for (int j = 0; j < 8; ++j) hh[j] = (f16)h[c*8 + j];
      *(f16x8*)&sH[t*SHS + c*8] = hh;
    }
  }
  __syncthreads();

  #pragma unroll
  for (int s = 0; s < 3; ++s){
    const float a0 = b_o0[s*16 + l16];
    #pragma unroll
    for (int i = 0; i < 4; ++i) acc[i][s] = (f32x4){a0, a0, a0, a0};
  }

  for (int l = 0; l < NBLK; ++l){
    const float* Wf = W_flr + l * NFILT * NPROP;
    const float* bf = b_flr + l * NPROP;
    const float* Ws = W_s   + l * NFILT * NAGG;
    const float* bs = b_s   + l * NAGG;
    const float* Wo = W_out + l * 228 * NFILT;
    const float* bo = b_out + l * NFILT;
    const float* g_ = bn_g  + l * NFILT;
    const float* be = bn_b  + l * NFILT;
    const float* bm = bn_m  + l * NFILT;
    const float* bv = bn_v  + l * NFILT;
    const f16*  fl  = frag + (size_t)l * 7 * 64 * 8;

    // ---- stage 1 (MFMA): feat = h @ [Wf|Ws]; f -> sFT f16, w = exp(-|d|) -> sW f32 ----
    {
      f16x8 b1f0, b1f1;
      if (frag){
        b1f0 = *(const f16x8*)&fl[(size_t)(0*64 + lane)*8];
        b1f1 = *(const f16x8*)&fl[(size_t)(1*64 + lane)*8];
      } else {
        #pragma unroll
        for (int j = 0; j < 8; ++j){
          const int k = kb*8 + j;
          b1f0[j] = (f16)Wf[k*NPROP + l16];
          const int n = 16 + l16;
          b1f1[j] = (f16)((n < 20) ? Wf[k*NPROP + n] : (n < 24 ? Ws[k*NAGG + (n-20)] : 0.f));
        }
      }
      const float bias0 = bf[l16];
      const int  c1 = 16 + l16;
      const float bias1 = (c1 < 20) ? bf[c1] : (c1 < 24 ? bs[c1-20] : 0.f);

      #pragma unroll
      for (int i = 0; i < 4; ++i){
        const int tb = wave*64 + i*16;
        const f16x8 a_ = *(const f16x8*)&sH[(tb + l16)*SHS + kb*8];
        f32x4 c0 = (f32x4){bias0, bias0, bias0, bias0};
        c0 = MFMA(a_, b1f0, c0);
        f16x4 s0;
        #pragma unroll
        for (int q = 0; q < 4; ++q) s0[q] = (f16)c0[q];
        *(f16x4*)&sFT[l16*SFTS + tb + kb*4] = s0;

        f32x4 c1v = (f32x4){bias1, bias1, bias1, bias1};
        c1v = MFMA(a_, b1f1, c1v);
        if (l16 < 4){
          f16x4 s1;
          #pragma unroll
          for (int q = 0; q < 4; ++q) s1[q] = (f16)c1v[q];
          *(f16x4*)&sFT[(16 + l16)*SFTS + tb + kb*4] = s1;
        } else if (l16 < 8){
          #pragma unroll
          for (int q = 0; q < 4; ++q)
            sW[(tb + kb*4 + q)*4 + (l16 - 4)] = __expf(-fabsf(c1v[q]));
        }
      }
    }
    __syncthreads();

    // ---- stage 2: partial max/sum over 512 rows; wave owns cols 3w..3w+2 ----
    // cols 0..19 = f (sFT), cols 20..23 = w (sW)
    {
      const int w3 = wave * 3;
      float psum[NAGG][3], pmax[NAGG][3];
      #pragma unroll
      for (int a = 0; a < NAGG; ++a)
        #pragma unroll
        for (int c = 0; c < 3; ++c){ psum[a][c] = 0.f; pmax[a][c] = -INFINITY; }
      for (int i = 0; i < 8; ++i){
        const int row = i * 64 + lane;
        const f32x4 wv = *(const f32x4*)&sW[row*4];
        float fc[3];
        #pragma unroll
        for (int c = 0; c < 3; ++c){
          const int col = w3 + c;
          fc[c] = (col < 20) ? (float)sFT[col*SFTS + row] : wv[col - 20];
        }
        #pragma unroll
        for (int a = 0; a < NAGG; ++a)
          #pragma unroll
          for (int c = 0; c < 3; ++c){
            const float p = wv[a] * fc[c];
            psum[a][c] += p;
            pmax[a][c]  = fmaxf(pmax[a][c], p);
          }
      }
      #pragma unroll
      for (int m = 32; m > 0; m >>= 1){
        #pragma unroll
        for (int a = 0; a < NAGG; ++a)
          #pragma unroll
          for (int c = 0; c < 3; ++c){
            psum[a][c] += __shfl_xor(psum[a][c], m, 64);
            pmax[a][c]  = fmaxf(pmax[a][c], __shfl_xor(pmax[a][c], m, 64));
          }
      }
      if (lane == 0){
        float* gp = wsF + WSF_AGG + (((size_t)(b*2 + (l&1))*2 + half) * NAGG * 48);
        #pragma unroll
        for (int a = 0; a < NAGG; ++a)
          #pragma unroll
          for (int c = 0; c < 3; ++c){
            sAgg[a][w3 + c]      = pmax[a][c];
            sAgg[a][24 + w3 + c] = psum[a][c];
            __hip_atomic_store(&gp[a*48 + w3 + c],      pmax[a][c], __ATOMIC_RELAXED, __HIP_MEMORY_SCOPE_AGENT);
            __hip_atomic_store(&gp[a*48 + 24 + w3 + c], psum[a][c], __ATOMIC_RELAXED, __HIP_MEMORY_SCOPE_AGENT);
          }
      }
    }
    __syncthreads();

    // ---- post flag; hide phaseC(l-1) in the partner-wait window ----
    if (t == 0){
      asm volatile("s_waitcnt vmcnt(0)" ::: "memory");
      __hip_atomic_fetch_add(flag, 1, __ATOMIC_RELAXED, __HIP_MEMORY_SCOPE_AGENT);
    }
    __builtin_amdgcn_sched_barrier(0);
    if (l > 0) phaseC(l - 1);            // sH still = out_{l-1}
    if (t == 0){
      while (__hip_atomic_load(flag, __ATOMIC_RELAXED, __HIP_MEMORY_SCOPE_AGENT) < 2*l + 4)
        __builtin_amdgcn_s_sleep(2);
    }
    __syncthreads();

    // ---- combine halves ----
    if (t < 192){
      const int a = t / 48, c = t - a * 48;
      const float* pp = wsF + WSF_AGG + (((size_t)(b*2 + (l&1))*2 + (half^1)) * NAGG * 48);
      const float mine   = sAgg[a][c];
      const float theirs = __hip_atomic_load(&pp[a*48 + c], __ATOMIC_RELAXED, __HIP_MEMORY_SCOPE_AGENT);
      sAgg[a][c] = (c < 24) ? fmaxf(mine, theirs) : (mine + theirs) * (1.0f / VV);
    }
    __syncthreads();

    // ---- M'[a][j] -> fp16 ----
    if (t < 128){
      const int a = t >> 5, j = t & 31;
      float m = Wo[(224 + a) * NFILT + j];
      #pragma unroll 8
      for (int c = 0; c < 48; ++c) m += sAgg[a][c] * Wo[(32 + a*48 + c) * NFILT + j];
      sMh[a*32 + j] = (f16)m;
    }
    __syncthreads();

    // ---- stage 3 (MFMA): o = h@WoH + w@M' + bo; h_new = bn(tanh(o)) -> sH ----
    {
      f16x8 b2f0, b2f1;
      if (frag){
        b2f0 = *(const f16x8*)&fl[(size_t)(2*64 + lane)*8];
        b2f1 = *(const f16x8*)&fl[(size_t)(3*64 + lane)*8];
      } else {
        #pragma unroll
        for (int j = 0; j < 8; ++j){
          const int k = kb*8 + j;
          b2f0[j] = (f16)Wo[k*NFILT + l16];
          b2f1[j] = (f16)Wo[k*NFILT + 16 + l16];
        }
      }
      f16x8 bmf[2];
      #pragma unroll
      for (int s = 0; s < 2; ++s)
        #pragma unroll
        for (int j = 0; j < 8; ++j)
          bmf[s][j] = (kb == 0 && j < 4) ? sMh[j*32 + s*16 + l16] : (f16)0.f;

      float boc[2], bmc[2], scc[2], bec[2];
      #pragma unroll
      for (int s = 0; s < 2; ++s){
        const int cc = s*16 + l16;
        boc[s] = bo[cc];
        bmc[s] = bm[cc];
        scc[s] = g_[cc] * rsqrtf(bv[cc] + BN_EPS);
        bec[s] = be[cc];
      }

      #pragma unroll
      for (int i = 0; i < 4; ++i){
        const int tb = wave*64 + i*16;
        const f16x8 a_ = *(const f16x8*)&sH[(tb + l16)*SHS + kb*8];
        f16x8 wa;
        #pragma unroll
        for (int j = 0; j < 8; ++j) wa[j] = (f16)0.f;
        {
          const f32x4 wv = *(const f32x4*)&sW[(tb + l16)*4];
          if (kb == 0){
            wa[0] = (f16)wv[0]; wa[1] = (f16)wv[1];
            wa[2] = (f16)wv[2]; wa[3] = (f16)wv[3];
          }
        }
        #pragma unroll
        for (int s = 0; s < 2; ++s){
          f32x4 o = (f32x4){0.f, 0.f, 0.f, 0.f};
          o = MFMA(a_, (s ? b2f1 : b2f0), o);
          o = MFMA(wa, bmf[s], o);
          #pragma unroll
          for (int q = 0; q < 4; ++q){
            const float th = fast_tanh(o[q] + boc[s]);
            const float hn = (th - bmc[s]) * scc[s] + bec[s];
            sH[(tb + kb*4 + q)*SHS + s*16 + l16] = (f16)hn;
          }
        }
      }
    }
    asm volatile("s_waitcnt lgkmcnt(0)" ::: "memory");
  }

  phaseC(NBLK - 1);

  // ---------------- head: out = relu(relu(acc) @ W_o1 + b_o1) ----------------
  {
    float w1c[3][3];
    #pragma unroll
    for (int s = 0; s < 3; ++s)
      #pragma unroll
      for (int m = 0; m < 3; ++m) w1c[s][m] = W_o1[(s*16 + l16)*3 + m];
    const float bo1_0 = b_o1[0], bo1_1 = b_o1[1], bo1_2 = b_o1[2];

    #pragma unroll
    for (int i = 0; i < 4; ++i){
      const int tb = wave*64 + i*16;
      float p[4][3];
      #pragma unroll
      for (int q = 0; q < 4; ++q){ p[q][0]=0.f; p[q][1]=0.f; p[q][2]=0.f; }
      #pragma unroll
      for (int s = 0; s < 3; ++s)
        #pragma unroll
        for (int q = 0; q < 4; ++q){
          const float r_ = fmaxf(acc[i][s][q], 0.f);
          p[q][0] += r_ * w1c[s][0];
          p[q][1] += r_ * w1c[s][1];
          p[q][2] += r_ * w1c[s][2];
        }
      #pragma unroll
      for (int m = 1; m <= 8; m <<= 1)
        #pragma unroll
        for (int q = 0; q < 4; ++q){
          p[q][0] += __shfl_xor(p[q][0], m, 64);
          p[q][1] += __shfl_xor(p[q][1], m, 64);
          p[q][2] += __shfl_xor(p[q][2], m, 64);
        }
      if (l16 < 3){
        const float bo1v = (l16 == 0) ? bo1_0 : ((l16 == 1) ? bo1_1 : bo1_2);
        #pragma unroll
        for (int q = 0; q < 4; ++q){
          const float vv = (l16 == 0) ? p[q][0] : ((l16 == 1) ? p[q][1] : p[q][2]);
          out[((size_t)b*VV + half*HV + tb + kb*4 + q)*3 + l16] = fmaxf(vv + bo1v, 0.f);
        }
      }
    }
  }
}

extern "C" void kernel_launch(void* const* d_in, const int* in_sizes, int n_in,
                              void* d_out, int out_size, void* d_ws, size_t ws_size,
                              hipStream_t stream) {
  const float* x      = (const float*)d_in[0];
  const float* bn0_g  = (const float*)d_in[1];
  const float* bn0_b  = (const float*)d_in[2];
  const float* bn0_m  = (const float*)d_in[3];
  const float* bn0_v  = (const float*)d_in[4];
  const float* W_in   = (const float*)d_in[5];
  const float* b_in   = (const float*)d_in[6];
  const float* W_flr  = (const float*)d_in[7];
  const float* b_flr  = (const float*)d_in[8];
  const float* W_s    = (const float*)d_in[9];
  const float* b_s    = (const float*)d_in[10];
  const float* W_out  = (const float*)d_in[11];
  const float* b_out  = (const float*)d_in[12];
  const float* bn_g   = (const float*)d_in[13];
  const float* bn_b   = (const float*)d_in[14];
  const float* bn_m   = (const float*)d_in[15];
  const float* bn_v   = (const float*)d_in[16];
  const float* W_o0   = (const float*)d_in[17];
  const float* b_o0   = (const float*)d_in[18];
  const float* W_o1   = (const float*)d_in[19];
  const float* b_o1   = (const float*)d_in[20];

  float* wsF = (float*)d_ws;
  const size_t needed = (size_t)WSF_FRAG * 4 + (size_t)NFRAG * 2;
  _Float16* frag = (ws_size >= needed) ? (_Float16*)(wsF + WSF_FRAG) : nullptr;

  hipMemsetAsync(d_ws, 0, BB * sizeof(int), stream);

  if (frag)
    garnet_prep<<<dim3((NFRAG + 255) / 256), dim3(256), 0, stream>>>(
        W_flr, W_s, W_out, W_o0, frag);

  garnet_fused<<<dim3(BB * 2), dim3(TPB), 0, stream>>>(
      x, bn0_g, bn0_b, bn0_m, bn0_v, W_in, b_in,
      W_flr, b_flr, W_s, b_s, W_out, b_out,
      bn_g, bn_b, bn_m, bn_v, W_o0, b_o0, W_o1, b_o1,
      (int*)d_ws, wsF, frag, (float*)d_out);
}